// Round 22
// baseline (193.400 us; speedup 1.0000x reference)
//
#include <hip/hip_runtime.h>
#include <hip/hip_bf16.h>

// FlashMultiHeadAttention: x -> QKV proj -> causal GQA flash attn -> out proj
// B=2 N=2048 E=2048 HQ=32 HKV=8 D=64 G=4. All compute in bf16 MFMA, fp32 accum.
// Q is pre-scaled by K2 = SCALE*log2(e) at projection time, so attention
// scores are already in log2 units (exp2(s - m) directly).

#define B_   2
#define N_   2048
#define E_   2048
#define HQ_  32
#define HKV_ 8
#define D_   64
#define BN_  (B_*N_)   // 4096 total rows

typedef __attribute__((ext_vector_type(8))) short bf16x8;
typedef __attribute__((ext_vector_type(4))) float f32x4;

#define MFMA16(a,b,c) __builtin_amdgcn_mfma_f32_16x16x32_bf16(a,b,c,0,0,0)

__device__ inline unsigned short f2bf(float f) {
  unsigned u = __builtin_bit_cast(unsigned, f);
  u += 0x7FFFu + ((u >> 16) & 1u);   // RNE
  return (unsigned short)(u >> 16);
}

// pack two f32 -> two truncated bf16 in one v_perm_b32 (P >= 0 so trunc = floor;
// <= 1 ulp (2^-8 rel) vs RNE, bias cancels in O/l). NOTE: v_cvt_pk_bf16_f32
// inline asm produced corrupt results on this toolchain (rounds 6 & 17) - do
// not reintroduce it.
__device__ inline unsigned pack_bf16_trunc(float lo, float hi) {
  return __builtin_amdgcn_perm(__builtin_bit_cast(unsigned, hi),
                               __builtin_bit_cast(unsigned, lo), 0x07060302u);
}

__device__ inline void gload_lds16(const void* g, void* l) {
  __builtin_amdgcn_global_load_lds(
      (const __attribute__((address_space(1))) void*)g,
      (__attribute__((address_space(3))) void*)l, 16, 0, 0);
}

// ---------------- fused cast fp32 -> bf16 for x,Wq,Wk,Wv,Wo ----------------
__global__ void cast_all(const float* __restrict__ x,  const float* __restrict__ wq,
                         const float* __restrict__ wk, const float* __restrict__ wv,
                         const float* __restrict__ wo, unsigned short* __restrict__ dst) {
  const int c0 = 2097152;            // x      (8388608 elems /4)
  const int c1 = c0 + 1048576;       // Wq
  const int c2 = c1 + 262144;        // Wk
  const int c3 = c2 + 262144;        // Wv
  const int c4 = c3 + 1048576;       // Wo
  int i = blockIdx.x * blockDim.x + threadIdx.x;
  const int stride = gridDim.x * blockDim.x;
  for (; i < c4; i += stride) {
    const float* src; int off;
    if      (i < c0) { src = x;  off = i; }
    else if (i < c1) { src = wq; off = i - c0; }
    else if (i < c2) { src = wk; off = i - c1; }
    else if (i < c3) { src = wv; off = i - c2; }
    else             { src = wo; off = i - c3; }
    float4 f = reinterpret_cast<const float4*>(src)[off];
    ushort4 u;
    u.x = f2bf(f.x); u.y = f2bf(f.y); u.z = f2bf(f.z); u.w = f2bf(f.w);
    reinterpret_cast<ushort4*>(dst)[i] = u;
  }
}

// ---------------- fused QKV projection GEMM: 128x192 tile, EXACT 2-blocks/CU ------
// (v15-verified) BM=128, BN=192 (virtual QKV cols 3072 = 16 x 192), BK=64.
// Grid 512 = exactly 2 per CU. 8 waves (2M x 4N), per-wave 64x48 (acc[4][3]).
// LDS dbuf: As[2][128x64] + Bs[2][192x64] = 80KB. Thin counted-vmcnt schedule.
// Q output (seg 0) is scaled by K2 = SCALE*log2(e) for log2-unit attn scores.
__global__ __launch_bounds__(512, 4) void gemm_qkv(
    const unsigned short* __restrict__ A,
    const unsigned short* __restrict__ Wq, const unsigned short* __restrict__ Wk,
    const unsigned short* __restrict__ Wv,
    const float* __restrict__ bq, const float* __restrict__ bk, const float* __restrict__ bv,
    unsigned short* __restrict__ Qo, unsigned short* __restrict__ Ko,
    unsigned short* __restrict__ Vto)
{
  __shared__ __align__(16) unsigned short As[2][8192];    // [buf][128*64]  2x16KB
  __shared__ __align__(16) unsigned short Bs[2][12288];   // [buf][192*64]  2x24KB
  const int tid  = threadIdx.x;
  const int w    = tid >> 6;
  const int lane = tid & 63;
  const int g    = blockIdx.x & 7;        // XCD slot
  const int s    = blockIdx.x >> 3;       // 0..63
  const int bm   = g*4 + (s >> 4);        // 0..31 (4 bm-panels per XCD)
  const int bn   = s & 15;                // 0..15
  const int m0   = bm << 7;
  const int n0v  = bn * 192;              // virtual col in [Q|K|V] = 3072
  const int K    = E_;
  const float K2S = 0.125f * 1.44269504088896340736f;   // SCALE * log2(e)

  const int mgrp = w >> 2;                // 0/1: rows mgrp*64
  const int ngrp = w & 3;                 // cols ngrp*48
  const int cl   = lane & 15;
  const int kgrp = lane >> 4;
  const int rl   = kgrp << 2;
  const int li   = lane >> 3;             // staging row-in-group 0..7
  const int lx   = lane & 7;              // staging chunk 0..7

  // staging bases; global chunk = lx^li (inverse swizzle)
  const unsigned gsw = ((unsigned)(lx ^ li)) << 3;   // elems
  const unsigned short* gA = A + (size_t)(m0 + w*16 + li) * K + gsw;
  const unsigned short* gBq[3];
  #pragma unroll
  for (int q = 0; q < 3; ++q) {
    const int vr = n0v + w*24 + q*8;      // seg-uniform (2048/2560 % 8 == 0)
    const unsigned short* base;
    if (vr < 2048)      base = Wq + (size_t)vr * K;
    else if (vr < 2560) base = Wk + (size_t)(vr - 2048) * K;
    else                base = Wv + (size_t)(vr - 2560) * K;
    gBq[q] = base + (size_t)li * K + gsw;
  }
  const unsigned aDst = (unsigned)(w*16)*64u + (unsigned)lane*8u;  // elems
  const unsigned bDst = (unsigned)(w*24)*64u + (unsigned)lane*8u;

  // read offsets (elems): row*64 + ((ks*4+kgrp)^(cl&7))*8
  unsigned rAo[4][2], rBo[3][2];
  #pragma unroll
  for (int ks = 0; ks < 2; ++ks) {
    const unsigned c8 = (((unsigned)(ks*4 + kgrp)) ^ (unsigned)(cl & 7)) << 3;
    #pragma unroll
    for (int z = 0; z < 4; ++z)
      rAo[z][ks] = (unsigned)(mgrp*64 + z*16 + cl) * 64u + c8;
    #pragma unroll
    for (int jj = 0; jj < 3; ++jj)
      rBo[jj][ks] = (unsigned)(ngrp*48 + jj*16 + cl) * 64u + c8;
  }

  f32x4 acc[4][3] = {};
  const int nt = K >> 6;   // 32

  auto STAGE = [&](int kt, int buf) {   // 5 wave-loads: 2 A + 3 B
    const int ko = kt << 6;
    #pragma unroll
    for (int q = 0; q < 2; ++q)
      gload_lds16(gA + (size_t)(q*8)*K + ko, &As[buf][aDst + q*512u]);
    #pragma unroll
    for (int q = 0; q < 3; ++q)
      gload_lds16(gBq[q] + ko, &Bs[buf][bDst + q*512u]);
  };

  STAGE(0, 0);
  int p = 0;

  for (int t = 0; t < nt; ++t) {
    if (t + 1 < nt) {
      STAGE(t + 1, p ^ 1);
      asm volatile("s_waitcnt vmcnt(5)" ::: "memory");   // tile-t landed
    } else {
      asm volatile("s_waitcnt vmcnt(0)" ::: "memory");
    }
    __builtin_amdgcn_s_barrier();
    #pragma unroll
    for (int ks = 0; ks < 2; ++ks) {
      bf16x8 af[4], bfr[3];
      #pragma unroll
      for (int z = 0; z < 4; ++z)
        af[z] = *reinterpret_cast<const bf16x8*>(&As[p][rAo[z][ks]]);
      #pragma unroll
      for (int jj = 0; jj < 3; ++jj)
        bfr[jj] = *reinterpret_cast<const bf16x8*>(&Bs[p][rBo[jj][ks]]);
      __builtin_amdgcn_s_setprio(1);
      #pragma unroll
      for (int z = 0; z < 4; ++z)
        #pragma unroll
        for (int jj = 0; jj < 3; ++jj)
          acc[z][jj] = MFMA16(af[z], bfr[jj], acc[z][jj]);
      __builtin_amdgcn_s_setprio(0);
    }
    __builtin_amdgcn_s_barrier();   // reads consumed -> safe to restage buf p
    p ^= 1;
  }

  // epilogue: per-(jj) 16-col fragment is segment-uniform (2048/2560 % 16 == 0)
  #pragma unroll
  for (int z = 0; z < 4; ++z) {
    const int rowb = m0 + mgrp*64 + z*16 + rl;
    #pragma unroll
    for (int jj = 0; jj < 3; ++jj) {
      const int col16 = n0v + ngrp*48 + jj*16;
      if (col16 < 2048) {
        const int col = col16 + cl;
        const float bj = bq[col];
        #pragma unroll
        for (int r = 0; r < 4; ++r)
          Qo[(size_t)(rowb + r) * 2048 + col] = f2bf((acc[z][jj][r] + bj) * K2S);
      } else if (col16 < 2560) {
        const int col = col16 - 2048 + cl;
        const float bj = bk[col];
        #pragma unroll
        for (int r = 0; r < 4; ++r)
          Ko[(size_t)(rowb + r) * 512 + col] = f2bf(acc[z][jj][r] + bj);
      } else {
        const int col = col16 - 2560 + cl;
        const float bj = bv[col];
        ushort4 u;
        u.x = f2bf(acc[z][jj][0] + bj);
        u.y = f2bf(acc[z][jj][1] + bj);
        u.z = f2bf(acc[z][jj][2] + bj);
        u.w = f2bf(acc[z][jj][3] + bj);
        *reinterpret_cast<ushort4*>(&Vto[(size_t)col * 4096 + rowb]) = u;
      }
    }
  }
}

// ---------------- out-proj GEMM: v15 engine, BM=128 BN=128 BK=64, fp32 out --------
// (v21-verified) Grid 512 = exact 2 blocks/CU (LDS 64KB each). 512 thr = 8 waves
// (2M x 4N), per-wave 64x32 (acc[4][2]). Thin counted-vmcnt dbuf schedule.
__global__ __launch_bounds__(512, 4) void gemm_out(
    const unsigned short* __restrict__ A, const unsigned short* __restrict__ W,
    const float* __restrict__ bias, float* __restrict__ C)
{
  __shared__ __align__(16) unsigned short As[2][8192];    // [buf][128*64]  2x16KB
  __shared__ __align__(16) unsigned short Bs[2][8192];    // [buf][128*64]  2x16KB
  const int tid  = threadIdx.x;
  const int w    = tid >> 6;
  const int lane = tid & 63;
  const int g    = blockIdx.x & 7;        // XCD slot
  const int s    = blockIdx.x >> 3;       // 0..63
  const int bm   = g*4 + (s >> 4);        // 0..31 (4 bm-panels per XCD)
  const int bn   = s & 15;                // 0..15
  const int m0   = bm << 7;
  const int n0   = bn << 7;
  const int K    = E_;

  const int mgrp = w >> 2;                // 0/1: rows mgrp*64
  const int ngrp = w & 3;                 // cols ngrp*32
  const int cl   = lane & 15;
  const int kgrp = lane >> 4;
  const int rl   = kgrp << 2;
  const int li   = lane >> 3;             // staging row-in-group 0..7
  const int lx   = lane & 7;              // staging chunk 0..7

  // staging bases; global chunk = lx^li (inverse swizzle)
  const unsigned gsw = ((unsigned)(lx ^ li)) << 3;   // elems
  const unsigned short* gA = A + (size_t)(m0 + w*16 + li) * K + gsw;
  const unsigned short* gB = W + (size_t)(n0 + w*16 + li) * K + gsw;
  const unsigned dSt = (unsigned)(w*16)*64u + (unsigned)lane*8u;   // elems

  // read offsets (elems): row*64 + ((ks*4+kgrp)^(cl&7))*8
  unsigned rAo[4][2], rBo[2][2];
  #pragma unroll
  for (int ks = 0; ks < 2; ++ks) {
    const unsigned c8 = (((unsigned)(ks*4 + kgrp)) ^ (unsigned)(cl & 7)) << 3;
    #pragma unroll
    for (int z = 0; z < 4; ++z)
      rAo[z][ks] = (unsigned)(mgrp*64 + z*16 + cl) * 64u + c8;
    #pragma unroll
    for (int jj = 0; jj < 2; ++jj)
      rBo[jj][ks] = (unsigned)(ngrp*32 + jj*16 + cl) * 64u + c8;
  }

  f32x4 acc[4][2] = {};
  const int nt = K >> 6;   // 32

  auto STAGE = [&](int kt, int buf) {   // 4 wave-loads: 2 A + 2 B
    const int ko = kt << 6;
    #pragma unroll
    for (int q = 0; q < 2; ++q)
      gload_lds16(gA + (size_t)(q*8)*K + ko, &As[buf][dSt + q*512u]);
    #pragma unroll
    for (int q = 0; q < 2; ++q)
      gload_lds16(gB + (size_t)(q*8)*K + ko, &Bs[buf][dSt + q*512u]);
  };

  STAGE(0, 0);
  int p = 0;

  for (int t = 0; t < nt; ++t) {
    if (t + 1 < nt) {
      STAGE(t + 1, p ^ 1);
      asm volatile("s_waitcnt vmcnt(4)" ::: "memory");   // tile-t landed
    } else {
      asm volatile("s_waitcnt vmcnt(0)" ::: "memory");
    }
    __builtin_amdgcn_s_barrier();
    #pragma unroll
    for (int ks = 0; ks < 2; ++ks) {
      bf16x8 af[4], bfr[2];
      #pragma unroll
      for (int z = 0; z < 4; ++z)
        af[z] = *reinterpret_cast<const bf16x8*>(&As[p][rAo[z][ks]]);
      #pragma unroll
      for (int jj = 0; jj < 2; ++jj)
        bfr[jj] = *reinterpret_cast<const bf16x8*>(&Bs[p][rBo[jj][ks]]);
      __builtin_amdgcn_s_setprio(1);
      #pragma unroll
      for (int z = 0; z < 4; ++z)
        #pragma unroll
        for (int jj = 0; jj < 2; ++jj)
          acc[z][jj] = MFMA16(af[z], bfr[jj], acc[z][jj]);
      __builtin_amdgcn_s_setprio(0);
    }
    __builtin_amdgcn_s_barrier();   // reads consumed -> safe to restage buf p
    p ^= 1;
  }

  // epilogue: fp32 + bias
  #pragma unroll
  for (int z = 0; z < 4; ++z) {
    const int rowb = m0 + mgrp*64 + z*16 + rl;
    #pragma unroll
    for (int jj = 0; jj < 2; ++jj) {
      const int col = n0 + ngrp*32 + jj*16 + cl;
      const float bj = bias[col];
      #pragma unroll
      for (int r = 0; r < 4; ++r)
        C[(size_t)(rowb + r) * E_ + col] = acc[z][jj][r] + bj;
    }
  }
}

// ---------------- causal GQA flash attention (v22: 4 blocks/CU) -------------------
// grid (16, 64): x = bh = b*8+h (-> XCD h via %8 dispatch), y: strip index
// sidx = 63 - y (longest-first). Block = 4 waves = the 4 query heads sharing
// (b,h)'s K/V, one 32-row strip. Ps halved to 8KB ([4][1024]) by processing
// i-blocks SEQUENTIALLY through one per-wave P slot (same-wave LDS ops are
// in-order -> WAR on the reused slot is safe; same pattern as cross-tile Ps
// reuse verified since v5). LDS 40KB -> EXACT 4 blocks/CU (160KB), 16 waves/CU.
// Engine otherwise = v20/v21 (verified): log2-unit scores, defer-max, max3
// tree, v_perm P-pack, ones-MFMA l, O^T = mfma(V^T, P).
__global__ __launch_bounds__(256, 4) void attn_kernel(
    const unsigned short* __restrict__ Q, const unsigned short* __restrict__ K,
    const unsigned short* __restrict__ Vt, unsigned short* __restrict__ O)
{
  __shared__ __align__(16) unsigned short Kbuf[2][4096];   // [64 kv][64 d] swizzled
  __shared__ __align__(16) unsigned short Vbuf[2][4096];   // [64 d][64 kv] swizzled
  __shared__ __align__(16) unsigned short Ps[4][1024];     // per-wave P slot (2KB)
  const int tid  = threadIdx.x;
  const int w    = tid >> 6;
  const int lane = tid & 63;
  const int bh   = blockIdx.x;      // b*8 + h
  const int b    = bh >> 3;
  const int h    = bh & 7;
  const int sidx = 63 - (int)blockIdx.y;   // strip 63..0 (longest first)
  const int hq   = h*4 + w;         // this wave's query head
  const int cl   = lane & 15;
  const int kgrp = lane >> 4;
  const int rl   = kgrp << 2;
  const int li   = lane >> 3;       // 0..7 (staging row-in-group)
  const int lx   = lane & 7;        // 0..7 (staging chunk)

  const float THR = 3.0f;           // defer-max bound (log2 units): P <= 2^3 = 8

  char* pws = (char*)&Ps[w][0];
  const unsigned swz = ((unsigned)(cl & 7)) << 4;

  bf16x8 ones8;
  #pragma unroll
  for (int q = 0; q < 8; ++q) ones8[q] = (short)0x3F80;   // bf16 1.0

  const char* Kp = (const char*)(K + (size_t)(b*N_)*512 + h*64);
  const char* Vp = (const char*)(Vt + (size_t)(h*64)*BN_ + b*N_);

  // staging constants: instr i covers rows i*8+li; global chunk = (lx^li)
  const unsigned schunk = ((unsigned)(lx ^ li)) << 4;
  const unsigned kso  = (unsigned)li*1024u + schunk;   // + i*8192  + t*65536
  const unsigned vso  = (unsigned)li*8192u + schunk;   // + i*65536 + t*128
  const unsigned ldst = (unsigned)lane*16u;            // + i*1024

  // fragment read offsets: row z*16+cl, chunk (ks*4+kgrp)^(cl&7)
  unsigned rdo[4][2];
  #pragma unroll
  for (int z = 0; z < 4; ++z)
    #pragma unroll
    for (int ks = 0; ks < 2; ++ks)
      rdo[z][ks] = (unsigned)z*2048u + (unsigned)cl*128u
                 + ((((unsigned)ks*4u + (unsigned)kgrp) ^ (unsigned)(cl & 7)) << 4);

  // P LDS offsets (single i-slot): write b64 (4 kv), read b128 (8 kv)
  unsigned wb[4], rb[2];
  #pragma unroll
  for (int c = 0; c < 4; ++c)
    wb[c] = (unsigned)cl*128u + (((unsigned)c*32u + (unsigned)kgrp*8u) ^ swz);
  #pragma unroll
  for (int ks = 0; ks < 2; ++ks)
    rb[ks] = (unsigned)cl*128u + (((unsigned)ks*64u + (unsigned)kgrp*16u) ^ swz);

  const int q0 = sidx << 5;
  const int nt = (sidx >> 1) + 1;   // kv tiles of 64

  // Q fragments (B-operand): lane cl = q row
  bf16x8 qf[2][2];
  #pragma unroll
  for (int i = 0; i < 2; ++i) {
    const size_t qoff = (size_t)(b*N_ + q0 + i*16 + cl) * E_ + hq*64 + (kgrp << 3);
    qf[i][0] = *reinterpret_cast<const bf16x8*>(Q + qoff);
    qf[i][1] = *reinterpret_cast<const bf16x8*>(Q + qoff + 32);
  }

  f32x4 o[2][4] = {};
  f32x4 l4[2] = {};
  float m[2] = {-1e30f, -1e30f};

  // stage tile 0 into buffer 0 (each wave: 2 K + 2 V instructions)
  #pragma unroll
  for (int q = 0; q < 2; ++q) {
    const unsigned i = (unsigned)(w*2 + q);
    gload_lds16(Kp + (i*8192u + kso),  (char*)Kbuf[0] + (i*1024u + ldst));
    gload_lds16(Vp + (i*65536u + vso), (char*)Vbuf[0] + (i*1024u + ldst));
  }
  int cur = 0;
  __syncthreads();   // drain stage

  for (int t = 0; t < nt; ++t) {
    // ---- stage tile t+1 into other buffer (overlaps with compute below) ----
    if (t + 1 < nt) {
      const unsigned kt = (unsigned)(t + 1) * 65536u;
      const unsigned vt = (unsigned)(t + 1) * 128u;
      #pragma unroll
      for (int q = 0; q < 2; ++q) {
        const unsigned i = (unsigned)(w*2 + q);
        gload_lds16(Kp + (kt + i*8192u + kso),  (char*)Kbuf[cur^1] + (i*1024u + ldst));
        gload_lds16(Vp + (vt + i*65536u + vso), (char*)Vbuf[cur^1] + (i*1024u + ldst));
      }
    }

    // ---- K fragments from LDS ----
    bf16x8 kf[4][2];
    #pragma unroll
    for (int c = 0; c < 4; ++c)
      #pragma unroll
      for (int ks = 0; ks < 2; ++ks)
        kf[c][ks] = *reinterpret_cast<const bf16x8*>((const char*)Kbuf[cur] + rdo[c][ks]);

    // ---- S^T = K Q (log2 units; Q pre-scaled by K2) ----
    f32x4 s[2][4];
    #pragma unroll
    for (int i = 0; i < 2; ++i)
      #pragma unroll
      for (int c = 0; c < 4; ++c) {
        f32x4 z = {};
        z = MFMA16(kf[c][0], qf[i][0], z);
        z = MFMA16(kf[c][1], qf[i][1], z);
        s[i][c] = z;
      }

    // ---- causal mask (last tile only): kv > q -> -inf ----
    if (t == nt - 1) {
      const int kvb = t << 6;
      #pragma unroll
      for (int i = 0; i < 2; ++i) {
        const int qq = q0 + i*16 + cl;
        #pragma unroll
        for (int c = 0; c < 4; ++c)
          #pragma unroll
          for (int r = 0; r < 4; ++r)
            if (kvb + c*16 + rl + r > qq) s[i][c][r] = -1e30f;
      }
    }

    // ---- V fragments from LDS (before i-loop; independent of P slot) ----
    bf16x8 vf[4][2];
    #pragma unroll
    for (int db = 0; db < 4; ++db)
      #pragma unroll
      for (int ks = 0; ks < 2; ++ks)
        vf[db][ks] = *reinterpret_cast<const bf16x8*>((const char*)Vbuf[cur] + rdo[db][ks]);

    // ---- per i-block: defer-max softmax -> P slot -> l + PV MFMA ----
    #pragma unroll
    for (int i = 0; i < 2; ++i) {
      const float v0 = fmaxf(fmaxf(s[i][0][0], s[i][0][1]), s[i][0][2]);
      const float v1 = fmaxf(fmaxf(s[i][0][3], s[i][1][0]), s[i][1][1]);
      const float v2 = fmaxf(fmaxf(s[i][1][2], s[i][1][3]), s[i][2][0]);
      const float v3 = fmaxf(fmaxf(s[i][2][1], s[i][2][2]), s[i][2][3]);
      const float v4 = fmaxf(fmaxf(s[i][3][0], s[i][3][1]), s[i][3][2]);
      const float lm = fmaxf(fmaxf(fmaxf(v0, v1), v2),
                             fmaxf(fmaxf(v3, v4), s[i][3][3]));
      if (!__all(lm <= m[i] + THR)) {
        // rare path (first tile + occasional growth): exact reduce + rescale
        float tm = lm;
        tm = fmaxf(tm, __shfl_xor(tm, 16, 64));
        tm = fmaxf(tm, __shfl_xor(tm, 32, 64));
        const float mn = fmaxf(m[i], tm);
        const float al = __builtin_amdgcn_exp2f(m[i] - mn);
        m[i] = mn;
        l4[i] *= al;
        #pragma unroll
        for (int db = 0; db < 4; ++db) o[i][db] *= al;
      }
      const float mn = m[i];
      #pragma unroll
      for (int c = 0; c < 4; ++c) {
        const float e0 = __builtin_amdgcn_exp2f(s[i][c][0] - mn);
        const float e1 = __builtin_amdgcn_exp2f(s[i][c][1] - mn);
        const float e2 = __builtin_amdgcn_exp2f(s[i][c][2] - mn);
        const float e3 = __builtin_amdgcn_exp2f(s[i][c][3] - mn);
        uint2 u;
        u.x = pack_bf16_trunc(e0, e1);
        u.y = pack_bf16_trunc(e2, e3);
        *reinterpret_cast<uint2*>(pws + wb[c]) = u;
      }
      const bf16x8 pa0 = *reinterpret_cast<const bf16x8*>(pws + rb[0]);
      const bf16x8 pa1 = *reinterpret_cast<const bf16x8*>(pws + rb[1]);
      l4[i] = MFMA16(ones8, pa0, l4[i]);
      l4[i] = MFMA16(ones8, pa1, l4[i]);
      #pragma unroll
      for (int db = 0; db < 4; ++db) {
        o[i][db] = MFMA16(vf[db][0], pa0, o[i][db]);
        o[i][db] = MFMA16(vf[db][1], pa1, o[i][db]);
      }
    }

    __syncthreads();   // stage(t+1) drained + all waves done reading buf[cur]
    cur ^= 1;
  }

  // ---- epilogue: O[q][hq*64 + d] = o/l (RNE f2bf, 8B stores) ----
  #pragma unroll
  for (int i = 0; i < 2; ++i) {
    const float inv = 1.0f / l4[i][0];
    const size_t orow = (size_t)(b*N_ + q0 + i*16 + cl) * E_ + hq*64 + rl;
    #pragma unroll
    for (int db = 0; db < 4; ++db) {
      ushort4 u;
      u.x = f2bf(o[i][db][0] * inv);
      u.y = f2bf(o[i][db][1] * inv);
      u.z = f2bf(o[i][db][2] * inv);
      u.w = f2bf(o[i][db][3] * inv);
      *reinterpret_cast<ushort4*>(&O[orow + db*16]) = u;
    }
  }
}

extern "C" void kernel_launch(void* const* d_in, const int* in_sizes, int n_in,
                              void* d_out, int out_size, void* d_ws, size_t ws_size,
                              hipStream_t stream) {
  const float* x  = (const float*)d_in[0];
  const float* Wq = (const float*)d_in[1];
  const float* bq = (const float*)d_in[2];
  const float* Wk = (const float*)d_in[3];
  const float* bk = (const float*)d_in[4];
  const float* Wv = (const float*)d_in[5];
  const float* bv = (const float*)d_in[6];
  const float* Wo = (const float*)d_in[7];
  const float* bo = (const float*)d_in[8];
  float* out = (float*)d_out;

  // workspace carve (bf16 elements); cast destinations contiguous in input order
  unsigned short* ws  = (unsigned short*)d_ws;
  unsigned short* xb  = ws;              // 4096x2048
  unsigned short* Wqb = xb  + 8388608;   // 2048x2048
  unsigned short* Wkb = Wqb + 4194304;   // 512x2048
  unsigned short* Wvb = Wkb + 1048576;   // 512x2048
  unsigned short* Wob = Wvb + 1048576;   // 2048x2048
  unsigned short* Qb  = Wob + 4194304;   // 4096x2048
  unsigned short* Kb  = Qb  + 8388608;   // 4096x512
  unsigned short* Vtb = Kb  + 2097152;   // 512x4096 (V transposed)
  unsigned short* Ob  = Vtb + 2097152;   // 4096x2048

  cast_all<<<dim3(2048), dim3(256), 0, stream>>>(x, Wq, Wk, Wv, Wo, xb);

  gemm_qkv<<<dim3(512), dim3(512), 0, stream>>>(xb, Wqb, Wkb, Wvb,
                                                bq, bk, bv, Qb, Kb, Vtb);

  attn_kernel<<<dim3(16, 64), dim3(256), 0, stream>>>(Qb, Kb, Vtb, Ob);

  gemm_out<<<dim3(512), dim3(512), 0, stream>>>(Ob, Wob, bo, out);
}

// Round 23
// 157.884 us; speedup vs baseline: 1.2249x; 1.2249x over previous
//
#include <hip/hip_runtime.h>
#include <hip/hip_bf16.h>

// FlashMultiHeadAttention: x -> QKV proj -> causal GQA flash attn -> out proj
// B=2 N=2048 E=2048 HQ=32 HKV=8 D=64 G=4. All compute in bf16 MFMA, fp32 accum.
// Q is pre-scaled by K2 = SCALE*log2(e) at projection time, so attention
// scores are already in log2 units (exp2(s - m) directly).

#define B_   2
#define N_   2048
#define E_   2048
#define HQ_  32
#define HKV_ 8
#define D_   64
#define BN_  (B_*N_)   // 4096 total rows

typedef __attribute__((ext_vector_type(8))) short bf16x8;
typedef __attribute__((ext_vector_type(4))) float f32x4;

#define MFMA16(a,b,c) __builtin_amdgcn_mfma_f32_16x16x32_bf16(a,b,c,0,0,0)

__device__ inline unsigned short f2bf(float f) {
  unsigned u = __builtin_bit_cast(unsigned, f);
  u += 0x7FFFu + ((u >> 16) & 1u);   // RNE
  return (unsigned short)(u >> 16);
}

// pack two f32 -> two truncated bf16 in one v_perm_b32 (P >= 0 so trunc = floor;
// <= 1 ulp (2^-8 rel) vs RNE, bias cancels in O/l). NOTE: v_cvt_pk_bf16_f32
// inline asm produced corrupt results on this toolchain (rounds 6 & 17) - do
// not reintroduce it. NOTE 2: __launch_bounds__(256,4) on attn drove the
// allocator to 64 VGPR -> massive scratch spills (round 22, WRITE_SIZE 91MB);
// keep (256,3).
__device__ inline unsigned pack_bf16_trunc(float lo, float hi) {
  return __builtin_amdgcn_perm(__builtin_bit_cast(unsigned, hi),
                               __builtin_bit_cast(unsigned, lo), 0x07060302u);
}

__device__ inline void gload_lds16(const void* g, void* l) {
  __builtin_amdgcn_global_load_lds(
      (const __attribute__((address_space(1))) void*)g,
      (__attribute__((address_space(3))) void*)l, 16, 0, 0);
}

// ---------------- fused cast fp32 -> bf16 for x,Wq,Wk,Wv,Wo ----------------
__global__ void cast_all(const float* __restrict__ x,  const float* __restrict__ wq,
                         const float* __restrict__ wk, const float* __restrict__ wv,
                         const float* __restrict__ wo, unsigned short* __restrict__ dst) {
  const int c0 = 2097152;            // x      (8388608 elems /4)
  const int c1 = c0 + 1048576;       // Wq
  const int c2 = c1 + 262144;        // Wk
  const int c3 = c2 + 262144;        // Wv
  const int c4 = c3 + 1048576;       // Wo
  int i = blockIdx.x * blockDim.x + threadIdx.x;
  const int stride = gridDim.x * blockDim.x;
  for (; i < c4; i += stride) {
    const float* src; int off;
    if      (i < c0) { src = x;  off = i; }
    else if (i < c1) { src = wq; off = i - c0; }
    else if (i < c2) { src = wk; off = i - c1; }
    else if (i < c3) { src = wv; off = i - c2; }
    else             { src = wo; off = i - c3; }
    float4 f = reinterpret_cast<const float4*>(src)[off];
    ushort4 u;
    u.x = f2bf(f.x); u.y = f2bf(f.y); u.z = f2bf(f.z); u.w = f2bf(f.w);
    reinterpret_cast<ushort4*>(dst)[i] = u;
  }
}

// ---------------- fused QKV projection GEMM: 128x192 tile, EXACT 2-blocks/CU ------
// (v15-verified) BM=128, BN=192 (virtual QKV cols 3072 = 16 x 192), BK=64.
// Grid 512 = exactly 2 per CU. 8 waves (2M x 4N), per-wave 64x48 (acc[4][3]).
// LDS dbuf: As[2][128x64] + Bs[2][192x64] = 80KB. Thin counted-vmcnt schedule.
// Q output (seg 0) is scaled by K2 = SCALE*log2(e) for log2-unit attn scores.
__global__ __launch_bounds__(512, 4) void gemm_qkv(
    const unsigned short* __restrict__ A,
    const unsigned short* __restrict__ Wq, const unsigned short* __restrict__ Wk,
    const unsigned short* __restrict__ Wv,
    const float* __restrict__ bq, const float* __restrict__ bk, const float* __restrict__ bv,
    unsigned short* __restrict__ Qo, unsigned short* __restrict__ Ko,
    unsigned short* __restrict__ Vto)
{
  __shared__ __align__(16) unsigned short As[2][8192];    // [buf][128*64]  2x16KB
  __shared__ __align__(16) unsigned short Bs[2][12288];   // [buf][192*64]  2x24KB
  const int tid  = threadIdx.x;
  const int w    = tid >> 6;
  const int lane = tid & 63;
  const int g    = blockIdx.x & 7;        // XCD slot
  const int s    = blockIdx.x >> 3;       // 0..63
  const int bm   = g*4 + (s >> 4);        // 0..31 (4 bm-panels per XCD)
  const int bn   = s & 15;                // 0..15
  const int m0   = bm << 7;
  const int n0v  = bn * 192;              // virtual col in [Q|K|V] = 3072
  const int K    = E_;
  const float K2S = 0.125f * 1.44269504088896340736f;   // SCALE * log2(e)

  const int mgrp = w >> 2;                // 0/1: rows mgrp*64
  const int ngrp = w & 3;                 // cols ngrp*48
  const int cl   = lane & 15;
  const int kgrp = lane >> 4;
  const int rl   = kgrp << 2;
  const int li   = lane >> 3;             // staging row-in-group 0..7
  const int lx   = lane & 7;              // staging chunk 0..7

  // staging bases; global chunk = lx^li (inverse swizzle)
  const unsigned gsw = ((unsigned)(lx ^ li)) << 3;   // elems
  const unsigned short* gA = A + (size_t)(m0 + w*16 + li) * K + gsw;
  const unsigned short* gBq[3];
  #pragma unroll
  for (int q = 0; q < 3; ++q) {
    const int vr = n0v + w*24 + q*8;      // seg-uniform (2048/2560 % 8 == 0)
    const unsigned short* base;
    if (vr < 2048)      base = Wq + (size_t)vr * K;
    else if (vr < 2560) base = Wk + (size_t)(vr - 2048) * K;
    else                base = Wv + (size_t)(vr - 2560) * K;
    gBq[q] = base + (size_t)li * K + gsw;
  }
  const unsigned aDst = (unsigned)(w*16)*64u + (unsigned)lane*8u;  // elems
  const unsigned bDst = (unsigned)(w*24)*64u + (unsigned)lane*8u;

  // read offsets (elems): row*64 + ((ks*4+kgrp)^(cl&7))*8
  unsigned rAo[4][2], rBo[3][2];
  #pragma unroll
  for (int ks = 0; ks < 2; ++ks) {
    const unsigned c8 = (((unsigned)(ks*4 + kgrp)) ^ (unsigned)(cl & 7)) << 3;
    #pragma unroll
    for (int z = 0; z < 4; ++z)
      rAo[z][ks] = (unsigned)(mgrp*64 + z*16 + cl) * 64u + c8;
    #pragma unroll
    for (int jj = 0; jj < 3; ++jj)
      rBo[jj][ks] = (unsigned)(ngrp*48 + jj*16 + cl) * 64u + c8;
  }

  f32x4 acc[4][3] = {};
  const int nt = K >> 6;   // 32

  auto STAGE = [&](int kt, int buf) {   // 5 wave-loads: 2 A + 3 B
    const int ko = kt << 6;
    #pragma unroll
    for (int q = 0; q < 2; ++q)
      gload_lds16(gA + (size_t)(q*8)*K + ko, &As[buf][aDst + q*512u]);
    #pragma unroll
    for (int q = 0; q < 3; ++q)
      gload_lds16(gBq[q] + ko, &Bs[buf][bDst + q*512u]);
  };

  STAGE(0, 0);
  int p = 0;

  for (int t = 0; t < nt; ++t) {
    if (t + 1 < nt) {
      STAGE(t + 1, p ^ 1);
      asm volatile("s_waitcnt vmcnt(5)" ::: "memory");   // tile-t landed
    } else {
      asm volatile("s_waitcnt vmcnt(0)" ::: "memory");
    }
    __builtin_amdgcn_s_barrier();
    #pragma unroll
    for (int ks = 0; ks < 2; ++ks) {
      bf16x8 af[4], bfr[3];
      #pragma unroll
      for (int z = 0; z < 4; ++z)
        af[z] = *reinterpret_cast<const bf16x8*>(&As[p][rAo[z][ks]]);
      #pragma unroll
      for (int jj = 0; jj < 3; ++jj)
        bfr[jj] = *reinterpret_cast<const bf16x8*>(&Bs[p][rBo[jj][ks]]);
      __builtin_amdgcn_s_setprio(1);
      #pragma unroll
      for (int z = 0; z < 4; ++z)
        #pragma unroll
        for (int jj = 0; jj < 3; ++jj)
          acc[z][jj] = MFMA16(af[z], bfr[jj], acc[z][jj]);
      __builtin_amdgcn_s_setprio(0);
    }
    __builtin_amdgcn_s_barrier();   // reads consumed -> safe to restage buf p
    p ^= 1;
  }

  // epilogue: per-(jj) 16-col fragment is segment-uniform (2048/2560 % 16 == 0)
  #pragma unroll
  for (int z = 0; z < 4; ++z) {
    const int rowb = m0 + mgrp*64 + z*16 + rl;
    #pragma unroll
    for (int jj = 0; jj < 3; ++jj) {
      const int col16 = n0v + ngrp*48 + jj*16;
      if (col16 < 2048) {
        const int col = col16 + cl;
        const float bj = bq[col];
        #pragma unroll
        for (int r = 0; r < 4; ++r)
          Qo[(size_t)(rowb + r) * 2048 + col] = f2bf((acc[z][jj][r] + bj) * K2S);
      } else if (col16 < 2560) {
        const int col = col16 - 2048 + cl;
        const float bj = bk[col];
        #pragma unroll
        for (int r = 0; r < 4; ++r)
          Ko[(size_t)(rowb + r) * 512 + col] = f2bf(acc[z][jj][r] + bj);
      } else {
        const int col = col16 - 2560 + cl;
        const float bj = bv[col];
        ushort4 u;
        u.x = f2bf(acc[z][jj][0] + bj);
        u.y = f2bf(acc[z][jj][1] + bj);
        u.z = f2bf(acc[z][jj][2] + bj);
        u.w = f2bf(acc[z][jj][3] + bj);
        *reinterpret_cast<ushort4*>(&Vto[(size_t)col * 4096 + rowb]) = u;
      }
    }
  }
}

// ---------------- out-proj GEMM: v15 engine, BM=128 BN=128 BK=64, fp32 out --------
// (v21-verified) Grid 512 = exact 2 blocks/CU (LDS 64KB each). 512 thr = 8 waves
// (2M x 4N), per-wave 64x32 (acc[4][2]). Thin counted-vmcnt dbuf schedule.
__global__ __launch_bounds__(512, 4) void gemm_out(
    const unsigned short* __restrict__ A, const unsigned short* __restrict__ W,
    const float* __restrict__ bias, float* __restrict__ C)
{
  __shared__ __align__(16) unsigned short As[2][8192];    // [buf][128*64]  2x16KB
  __shared__ __align__(16) unsigned short Bs[2][8192];    // [buf][128*64]  2x16KB
  const int tid  = threadIdx.x;
  const int w    = tid >> 6;
  const int lane = tid & 63;
  const int g    = blockIdx.x & 7;        // XCD slot
  const int s    = blockIdx.x >> 3;       // 0..63
  const int bm   = g*4 + (s >> 4);        // 0..31 (4 bm-panels per XCD)
  const int bn   = s & 15;                // 0..15
  const int m0   = bm << 7;
  const int n0   = bn << 7;
  const int K    = E_;

  const int mgrp = w >> 2;                // 0/1: rows mgrp*64
  const int ngrp = w & 3;                 // cols ngrp*32
  const int cl   = lane & 15;
  const int kgrp = lane >> 4;
  const int rl   = kgrp << 2;
  const int li   = lane >> 3;             // staging row-in-group 0..7
  const int lx   = lane & 7;              // staging chunk 0..7

  // staging bases; global chunk = lx^li (inverse swizzle)
  const unsigned gsw = ((unsigned)(lx ^ li)) << 3;   // elems
  const unsigned short* gA = A + (size_t)(m0 + w*16 + li) * K + gsw;
  const unsigned short* gB = W + (size_t)(n0 + w*16 + li) * K + gsw;
  const unsigned dSt = (unsigned)(w*16)*64u + (unsigned)lane*8u;   // elems

  // read offsets (elems): row*64 + ((ks*4+kgrp)^(cl&7))*8
  unsigned rAo[4][2], rBo[2][2];
  #pragma unroll
  for (int ks = 0; ks < 2; ++ks) {
    const unsigned c8 = (((unsigned)(ks*4 + kgrp)) ^ (unsigned)(cl & 7)) << 3;
    #pragma unroll
    for (int z = 0; z < 4; ++z)
      rAo[z][ks] = (unsigned)(mgrp*64 + z*16 + cl) * 64u + c8;
    #pragma unroll
    for (int jj = 0; jj < 2; ++jj)
      rBo[jj][ks] = (unsigned)(ngrp*32 + jj*16 + cl) * 64u + c8;
  }

  f32x4 acc[4][2] = {};
  const int nt = K >> 6;   // 32

  auto STAGE = [&](int kt, int buf) {   // 4 wave-loads: 2 A + 2 B
    const int ko = kt << 6;
    #pragma unroll
    for (int q = 0; q < 2; ++q)
      gload_lds16(gA + (size_t)(q*8)*K + ko, &As[buf][dSt + q*512u]);
    #pragma unroll
    for (int q = 0; q < 2; ++q)
      gload_lds16(gB + (size_t)(q*8)*K + ko, &Bs[buf][dSt + q*512u]);
  };

  STAGE(0, 0);
  int p = 0;

  for (int t = 0; t < nt; ++t) {
    if (t + 1 < nt) {
      STAGE(t + 1, p ^ 1);
      asm volatile("s_waitcnt vmcnt(4)" ::: "memory");   // tile-t landed
    } else {
      asm volatile("s_waitcnt vmcnt(0)" ::: "memory");
    }
    __builtin_amdgcn_s_barrier();
    #pragma unroll
    for (int ks = 0; ks < 2; ++ks) {
      bf16x8 af[4], bfr[2];
      #pragma unroll
      for (int z = 0; z < 4; ++z)
        af[z] = *reinterpret_cast<const bf16x8*>(&As[p][rAo[z][ks]]);
      #pragma unroll
      for (int jj = 0; jj < 2; ++jj)
        bfr[jj] = *reinterpret_cast<const bf16x8*>(&Bs[p][rBo[jj][ks]]);
      __builtin_amdgcn_s_setprio(1);
      #pragma unroll
      for (int z = 0; z < 4; ++z)
        #pragma unroll
        for (int jj = 0; jj < 2; ++jj)
          acc[z][jj] = MFMA16(af[z], bfr[jj], acc[z][jj]);
      __builtin_amdgcn_s_setprio(0);
    }
    __builtin_amdgcn_s_barrier();   // reads consumed -> safe to restage buf p
    p ^= 1;
  }

  // epilogue: fp32 + bias
  #pragma unroll
  for (int z = 0; z < 4; ++z) {
    const int rowb = m0 + mgrp*64 + z*16 + rl;
    #pragma unroll
    for (int jj = 0; jj < 2; ++jj) {
      const int col = n0 + ngrp*32 + jj*16 + cl;
      const float bj = bias[col];
      #pragma unroll
      for (int r = 0; r < 4; ++r)
        C[(size_t)(rowb + r) * E_ + col] = acc[z][jj][r] + bj;
    }
  }
}

// ---------------- causal GQA flash attention (v21-exact: log2-unit scores) --------
// grid (16, 64): x = bh = b*8+h (-> XCD h via %8 dispatch), y: strip index
// sidx = 63 - y (longest-first). Block = 4 waves = the 4 query heads sharing
// (b,h)'s K/V, one 32-row strip, 3 blocks/CU. Q pre-scaled by K2 at projection,
// so exp2(s - m) directly; THR = 3.0 (log2 units, P <= 8); max3-fusable tree;
// v_perm P-pack; defer-max; ones-MFMA l; O^T = mfma(V^T, P).
__global__ __launch_bounds__(256, 3) void attn_kernel(
    const unsigned short* __restrict__ Q, const unsigned short* __restrict__ K,
    const unsigned short* __restrict__ Vt, unsigned short* __restrict__ O)
{
  __shared__ __align__(16) unsigned short Kbuf[2][4096];   // [64 kv][64 d] swizzled
  __shared__ __align__(16) unsigned short Vbuf[2][4096];   // [64 d][64 kv] swizzled
  __shared__ __align__(16) unsigned short Ps[4][2048];     // per-wave P
  const int tid  = threadIdx.x;
  const int w    = tid >> 6;
  const int lane = tid & 63;
  const int bh   = blockIdx.x;      // b*8 + h
  const int b    = bh >> 3;
  const int h    = bh & 7;
  const int sidx = 63 - (int)blockIdx.y;   // strip 63..0 (longest first)
  const int hq   = h*4 + w;         // this wave's query head
  const int cl   = lane & 15;
  const int kgrp = lane >> 4;
  const int rl   = kgrp << 2;
  const int li   = lane >> 3;       // 0..7 (staging row-in-group)
  const int lx   = lane & 7;        // 0..7 (staging chunk)

  const float THR = 3.0f;           // defer-max bound (log2 units): P <= 2^3 = 8

  char* pws = (char*)&Ps[w][0];
  const unsigned swz = ((unsigned)(cl & 7)) << 4;

  bf16x8 ones8;
  #pragma unroll
  for (int q = 0; q < 8; ++q) ones8[q] = (short)0x3F80;   // bf16 1.0

  const char* Kp = (const char*)(K + (size_t)(b*N_)*512 + h*64);
  const char* Vp = (const char*)(Vt + (size_t)(h*64)*BN_ + b*N_);

  // staging constants: instr i covers rows i*8+li; global chunk = (lx^li)
  const unsigned schunk = ((unsigned)(lx ^ li)) << 4;
  const unsigned kso  = (unsigned)li*1024u + schunk;   // + i*8192  + t*65536
  const unsigned vso  = (unsigned)li*8192u + schunk;   // + i*65536 + t*128
  const unsigned ldst = (unsigned)lane*16u;            // + i*1024

  // fragment read offsets: row z*16+cl, chunk (ks*4+kgrp)^(cl&7)
  unsigned rdo[4][2];
  #pragma unroll
  for (int z = 0; z < 4; ++z)
    #pragma unroll
    for (int ks = 0; ks < 2; ++ks)
      rdo[z][ks] = (unsigned)z*2048u + (unsigned)cl*128u
                 + ((((unsigned)ks*4u + (unsigned)kgrp) ^ (unsigned)(cl & 7)) << 4);

  // P LDS offsets: write b64 (4 kv), read b128 (8 kv)
  unsigned wb[2][4], rb[2][2];
  #pragma unroll
  for (int i = 0; i < 2; ++i) {
    #pragma unroll
    for (int c = 0; c < 4; ++c)
      wb[i][c] = (unsigned)i*2048u + (unsigned)cl*128u
               + (((unsigned)c*32u + (unsigned)kgrp*8u) ^ swz);
    #pragma unroll
    for (int ks = 0; ks < 2; ++ks)
      rb[i][ks] = (unsigned)i*2048u + (unsigned)cl*128u
                + (((unsigned)ks*64u + (unsigned)kgrp*16u) ^ swz);
  }

  const int q0 = sidx << 5;
  const int nt = (sidx >> 1) + 1;   // kv tiles of 64

  // Q fragments (B-operand): lane cl = q row
  bf16x8 qf[2][2];
  #pragma unroll
  for (int i = 0; i < 2; ++i) {
    const size_t qoff = (size_t)(b*N_ + q0 + i*16 + cl) * E_ + hq*64 + (kgrp << 3);
    qf[i][0] = *reinterpret_cast<const bf16x8*>(Q + qoff);
    qf[i][1] = *reinterpret_cast<const bf16x8*>(Q + qoff + 32);
  }

  f32x4 o[2][4] = {};
  f32x4 l4[2] = {};
  float m[2] = {-1e30f, -1e30f};

  // stage tile 0 into buffer 0 (each wave: 2 K + 2 V instructions)
  #pragma unroll
  for (int q = 0; q < 2; ++q) {
    const unsigned i = (unsigned)(w*2 + q);
    gload_lds16(Kp + (i*8192u + kso),  (char*)Kbuf[0] + (i*1024u + ldst));
    gload_lds16(Vp + (i*65536u + vso), (char*)Vbuf[0] + (i*1024u + ldst));
  }
  int cur = 0;
  __syncthreads();   // drain stage

  for (int t = 0; t < nt; ++t) {
    // ---- stage tile t+1 into other buffer (overlaps with compute below) ----
    if (t + 1 < nt) {
      const unsigned kt = (unsigned)(t + 1) * 65536u;
      const unsigned vt = (unsigned)(t + 1) * 128u;
      #pragma unroll
      for (int q = 0; q < 2; ++q) {
        const unsigned i = (unsigned)(w*2 + q);
        gload_lds16(Kp + (kt + i*8192u + kso),  (char*)Kbuf[cur^1] + (i*1024u + ldst));
        gload_lds16(Vp + (vt + i*65536u + vso), (char*)Vbuf[cur^1] + (i*1024u + ldst));
      }
    }

    // ---- K fragments from LDS ----
    bf16x8 kf[4][2];
    #pragma unroll
    for (int c = 0; c < 4; ++c)
      #pragma unroll
      for (int ks = 0; ks < 2; ++ks)
        kf[c][ks] = *reinterpret_cast<const bf16x8*>((const char*)Kbuf[cur] + rdo[c][ks]);

    // ---- S^T = K Q (log2 units; Q pre-scaled by K2) ----
    f32x4 s[2][4];
    #pragma unroll
    for (int i = 0; i < 2; ++i)
      #pragma unroll
      for (int c = 0; c < 4; ++c) {
        f32x4 z = {};
        z = MFMA16(kf[c][0], qf[i][0], z);
        z = MFMA16(kf[c][1], qf[i][1], z);
        s[i][c] = z;
      }

    // ---- causal mask (last tile only): kv > q -> -inf ----
    if (t == nt - 1) {
      const int kvb = t << 6;
      #pragma unroll
      for (int i = 0; i < 2; ++i) {
        const int qq = q0 + i*16 + cl;
        #pragma unroll
        for (int c = 0; c < 4; ++c)
          #pragma unroll
          for (int r = 0; r < 4; ++r)
            if (kvb + c*16 + rl + r > qq) s[i][c][r] = -1e30f;
      }
    }

    // ---- softmax per i-block: DEFER-MAX (T13), max3 tree, v_perm P-pack ----
    #pragma unroll
    for (int i = 0; i < 2; ++i) {
      const float v0 = fmaxf(fmaxf(s[i][0][0], s[i][0][1]), s[i][0][2]);
      const float v1 = fmaxf(fmaxf(s[i][0][3], s[i][1][0]), s[i][1][1]);
      const float v2 = fmaxf(fmaxf(s[i][1][2], s[i][1][3]), s[i][2][0]);
      const float v3 = fmaxf(fmaxf(s[i][2][1], s[i][2][2]), s[i][2][3]);
      const float v4 = fmaxf(fmaxf(s[i][3][0], s[i][3][1]), s[i][3][2]);
      const float lm = fmaxf(fmaxf(fmaxf(v0, v1), v2),
                             fmaxf(fmaxf(v3, v4), s[i][3][3]));
      if (!__all(lm <= m[i] + THR)) {
        // rare path (first tile + occasional growth): exact reduce + rescale
        float tm = lm;
        tm = fmaxf(tm, __shfl_xor(tm, 16, 64));
        tm = fmaxf(tm, __shfl_xor(tm, 32, 64));
        const float mn = fmaxf(m[i], tm);
        const float al = __builtin_amdgcn_exp2f(m[i] - mn);
        m[i] = mn;
        l4[i] *= al;
        #pragma unroll
        for (int db = 0; db < 4; ++db) o[i][db] *= al;
      }
      const float mn = m[i];
      #pragma unroll
      for (int c = 0; c < 4; ++c) {
        const float e0 = __builtin_amdgcn_exp2f(s[i][c][0] - mn);
        const float e1 = __builtin_amdgcn_exp2f(s[i][c][1] - mn);
        const float e2 = __builtin_amdgcn_exp2f(s[i][c][2] - mn);
        const float e3 = __builtin_amdgcn_exp2f(s[i][c][3] - mn);
        uint2 u;
        u.x = pack_bf16_trunc(e0, e1);
        u.y = pack_bf16_trunc(e2, e3);
        *reinterpret_cast<uint2*>(pws + wb[i][c]) = u;
      }
    }

    // ---- V fragments from LDS ----
    bf16x8 vf[4][2];
    #pragma unroll
    for (int db = 0; db < 4; ++db)
      #pragma unroll
      for (int ks = 0; ks < 2; ++ks)
        vf[db][ks] = *reinterpret_cast<const bf16x8*>((const char*)Vbuf[cur] + rdo[db][ks]);

    // ---- O^T += V^T P ; l += 1 . P ----
    #pragma unroll
    for (int i = 0; i < 2; ++i) {
      const bf16x8 pa0 = *reinterpret_cast<const bf16x8*>(pws + rb[i][0]);
      const bf16x8 pa1 = *reinterpret_cast<const bf16x8*>(pws + rb[i][1]);
      l4[i] = MFMA16(ones8, pa0, l4[i]);
      l4[i] = MFMA16(ones8, pa1, l4[i]);
      #pragma unroll
      for (int db = 0; db < 4; ++db) {
        o[i][db] = MFMA16(vf[db][0], pa0, o[i][db]);
        o[i][db] = MFMA16(vf[db][1], pa1, o[i][db]);
      }
    }

    __syncthreads();   // stage(t+1) drained + all waves done reading buf[cur]
    cur ^= 1;
  }

  // ---- epilogue: O[q][hq*64 + d] = o/l (RNE f2bf, 8B stores) ----
  #pragma unroll
  for (int i = 0; i < 2; ++i) {
    const float inv = 1.0f / l4[i][0];
    const size_t orow = (size_t)(b*N_ + q0 + i*16 + cl) * E_ + hq*64 + rl;
    #pragma unroll
    for (int db = 0; db < 4; ++db) {
      ushort4 u;
      u.x = f2bf(o[i][db][0] * inv);
      u.y = f2bf(o[i][db][1] * inv);
      u.z = f2bf(o[i][db][2] * inv);
      u.w = f2bf(o[i][db][3] * inv);
      *reinterpret_cast<ushort4*>(&O[orow + db*16]) = u;
    }
  }
}

extern "C" void kernel_launch(void* const* d_in, const int* in_sizes, int n_in,
                              void* d_out, int out_size, void* d_ws, size_t ws_size,
                              hipStream_t stream) {
  const float* x  = (const float*)d_in[0];
  const float* Wq = (const float*)d_in[1];
  const float* bq = (const float*)d_in[2];
  const float* Wk = (const float*)d_in[3];
  const float* bk = (const float*)d_in[4];
  const float* Wv = (const float*)d_in[5];
  const float* bv = (const float*)d_in[6];
  const float* Wo = (const float*)d_in[7];
  const float* bo = (const float*)d_in[8];
  float* out = (float*)d_out;

  // workspace carve (bf16 elements); cast destinations contiguous in input order
  unsigned short* ws  = (unsigned short*)d_ws;
  unsigned short* xb  = ws;              // 4096x2048
  unsigned short* Wqb = xb  + 8388608;   // 2048x2048
  unsigned short* Wkb = Wqb + 4194304;   // 512x2048
  unsigned short* Wvb = Wkb + 1048576;   // 512x2048
  unsigned short* Wob = Wvb + 1048576;   // 2048x2048
  unsigned short* Qb  = Wob + 4194304;   // 4096x2048
  unsigned short* Kb  = Qb  + 8388608;   // 4096x512
  unsigned short* Vtb = Kb  + 2097152;   // 512x4096 (V transposed)
  unsigned short* Ob  = Vtb + 2097152;   // 4096x2048

  cast_all<<<dim3(2048), dim3(256), 0, stream>>>(x, Wq, Wk, Wv, Wo, xb);

  gemm_qkv<<<dim3(512), dim3(512), 0, stream>>>(xb, Wqb, Wkb, Wvb,
                                                bq, bk, bv, Qb, Kb, Vtb);

  attn_kernel<<<dim3(16, 64), dim3(256), 0, stream>>>(Qb, Kb, Vtb, Ob);

  gemm_out<<<dim3(512), dim3(512), 0, stream>>>(Ob, Wob, bo, out);
}